// Round 1
// baseline (1845.534 us; speedup 1.0000x reference)
//
#include <hip/hip_runtime.h>

#define Bn 512
#define Cn 202
#define Pn 27
#define Nn 729
#define CHn 200
#define Kn 58
#define OUTCn 64
#define CENTERn 364   // 13*27+13

// ---------------- Kernel A: build src permutation per batch ----------------
__global__ __launch_bounds__(256) void src_kernel(const float* __restrict__ x,
                                                  const int* __restrict__ rand_idx,
                                                  int* __restrict__ src_out) {
  int b = blockIdx.x;
  __shared__ float sp[Nn];
  __shared__ short M[Nn];
  __shared__ short z[Nn];
  __shared__ int s_num;
  int tid = threadIdx.x;
  const float* xsp = x + ((size_t)b * Cn + CHn) * Nn;
  for (int n = tid; n < Nn; n += 256) sp[n] = xsp[n];
  __syncthreads();
  float central = sp[CENTERn];
  __syncthreads();
  for (int k = tid; k < Kn; k += 256) sp[rand_idx[b * Kn + k]] = central;
  __syncthreads();
  if (tid == 0) {
    int cm = 0, cz = 0;
    for (int n = 0; n < Nn; ++n) {
      if (sp[n] == central) { M[cm] = (short)n; cm++; z[n] = -1; }
      else { z[n] = (short)cz; cz++; }
    }
    s_num = cm;
  }
  __syncthreads();
  int num_one = s_num;
  for (int n = tid; n < Nn; n += 256) {
    int zz = z[n];
    src_out[b * Nn + n] = (zz < 0) ? n : (int)M[zz % num_one];
  }
}

// ---------------- Kernel B: gathered 3x3 conv ----------------
// block = (batch b, output row i); 256 threads = 64 o * 4 j-groups
__global__ __launch_bounds__(256) void conv_kernel(const float* __restrict__ x,
                                                   const float* __restrict__ W,
                                                   const float* __restrict__ bias,
                                                   const int* __restrict__ src,
                                                   float* __restrict__ y) {
  int b = blockIdx.y;
  int i = blockIdx.x;
  int tid = threadIdx.x;
  int o = tid >> 2;
  int g = tid & 3;
  int j0 = g * 7;
  int nj = (g == 3) ? 6 : 7;

  __shared__ float feat[3][Pn + 3];  // cols: [0]=pad, [1..27]=j, [28],[29]=pad
  __shared__ int srcl[3 * Pn];

  for (int idx = tid; idx < 3 * Pn; idx += 256) {
    int r = idx / Pn, jj = idx - r * Pn;
    int row = i - 1 + r;
    srcl[idx] = (row >= 0 && row < Pn) ? src[b * Nn + row * Pn + jj] : -1;
  }
  if (tid < 3) {
    feat[tid][0] = 0.f;
    feat[tid][Pn + 1] = 0.f;
    feat[tid][Pn + 2] = 0.f;
  }

  float acc[7];
#pragma unroll
  for (int t = 0; t < 7; ++t) acc[t] = 0.f;

  const float* xb = x + (size_t)b * Cn * Nn;
  const float* wb = W + (size_t)o * CHn * 9;
  __syncthreads();

  for (int c = 0; c < CHn; ++c) {
    const float* xc = xb + (size_t)c * Nn;
    for (int idx = tid; idx < 3 * Pn; idx += 256) {
      int r = idx / Pn, jj = idx - r * Pn;
      int s = srcl[idx];
      feat[r][jj + 1] = (s >= 0) ? xc[s] : 0.f;
    }
    __syncthreads();

    float wr[9];
#pragma unroll
    for (int t = 0; t < 9; ++t) wr[t] = wb[c * 9 + t];

    float fw[3][9];
#pragma unroll
    for (int r = 0; r < 3; ++r)
#pragma unroll
      for (int k = 0; k < 9; ++k)
        fw[r][k] = feat[r][j0 + k];  // j0+k <= 21+8 = 29, in bounds

#pragma unroll
    for (int t = 0; t < 7; ++t) {
      float a = acc[t];
#pragma unroll
      for (int di = 0; di < 3; ++di)
#pragma unroll
        for (int dj = 0; dj < 3; ++dj)
          a += fw[di][t + dj] * wr[di * 3 + dj];
      acc[t] = a;
    }
    __syncthreads();
  }

#pragma unroll
  for (int t = 0; t < 7; ++t) {
    if (t < nj) {
      int j = j0 + t;
      y[(((size_t)b * OUTCn + o) * Pn + i) * Pn + j] = acc[t] + bias[o];
    }
  }
}

extern "C" void kernel_launch(void* const* d_in, const int* in_sizes, int n_in,
                              void* d_out, int out_size, void* d_ws, size_t ws_size,
                              hipStream_t stream) {
  const float* x = (const float*)d_in[0];
  const float* W = (const float*)d_in[1];
  const float* bias = (const float*)d_in[2];
  const int* rand_idx = (const int*)d_in[3];
  float* y = (float*)d_out;
  int* src = (int*)d_ws;  // 512*729 ints = 1.49 MB

  src_kernel<<<Bn, 256, 0, stream>>>(x, rand_idx, src);
  conv_kernel<<<dim3(Pn, Bn), 256, 0, stream>>>(x, W, bias, src, y);
}

// Round 2
// 257.968 us; speedup vs baseline: 7.1541x; 7.1541x over previous
//
#include <hip/hip_runtime.h>

#define Bn 512
#define Cn 202
#define Pn 27
#define Nn 729
#define CHn 200
#define Kn 58
#define OUTCn 64
#define CENTERn 364   // 13*27+13
#define CHP 224       // channels padded to 7 chunks of 32
#define NCHUNK 7
#define PP 29         // spatially padded image dim
#define CP2 40        // per-pixel channel stride in LDS (bf16 elems): 80B = 16B-aligned, 20 dwords -> even bank spread

typedef float f32x4 __attribute__((ext_vector_type(4)));
typedef short s16x8 __attribute__((ext_vector_type(8)));
typedef short s16x4 __attribute__((ext_vector_type(4)));

static __device__ __forceinline__ unsigned short f2bf(float f) {
  unsigned u = __float_as_uint(f);
  u += 0x7fffu + ((u >> 16) & 1u);   // RNE
  return (unsigned short)(u >> 16);
}

// ---------------- Kernel A: build src permutation per batch ----------------
__global__ __launch_bounds__(256) void src_kernel(const float* __restrict__ x,
                                                  const int* __restrict__ rand_idx,
                                                  int* __restrict__ src_out) {
  int b = blockIdx.x;
  __shared__ float sp[Nn];
  __shared__ short M[Nn];
  __shared__ short z[Nn];
  __shared__ int s_num;
  int tid = threadIdx.x;
  const float* xsp = x + ((size_t)b * Cn + CHn) * Nn;
  for (int n = tid; n < Nn; n += 256) sp[n] = xsp[n];
  __syncthreads();
  float central = sp[CENTERn];
  __syncthreads();
  for (int k = tid; k < Kn; k += 256) sp[rand_idx[b * Kn + k]] = central;
  __syncthreads();
  if (tid == 0) {
    int cm = 0, cz = 0;
    for (int n = 0; n < Nn; ++n) {
      if (sp[n] == central) { M[cm] = (short)n; cm++; z[n] = -1; }
      else { z[n] = (short)cz; cz++; }
    }
    s_num = cm;
  }
  __syncthreads();
  int num_one = s_num;
  for (int n = tid; n < Nn; n += 256) {
    int zz = z[n];
    src_out[b * Nn + n] = (zz < 0) ? n : (int)M[zz % num_one];
  }
}

// ---------------- Kernel B: repack weights to bf16 Wt[r][o][c], c padded to 224 ----------------
__global__ __launch_bounds__(256) void wprep_kernel(const float* __restrict__ W,
                                                    short* __restrict__ Wt) {
  int idx = blockIdx.x * 256 + threadIdx.x;
  if (idx >= 9 * OUTCn * CHP) return;
  int r = idx / (OUTCn * CHP);
  int rem = idx - r * (OUTCn * CHP);
  int o = rem / CHP;
  int c = rem - o * CHP;
  float v = (c < CHn) ? W[((size_t)o * CHn + c) * 9 + r] : 0.f;
  Wt[idx] = (short)f2bf(v);
}

// ---------------- Kernel C: fused gather + implicit-GEMM conv (MFMA) ----------------
// 1 block = 1 batch. 512 threads = 8 waves; wave w owns col-tiles [6w, 6w+6) (16 cols each),
// all 64 output channels (4 o-tiles). acc[4][6] f32x4.
__global__ __launch_bounds__(512, 2) void conv_kernel(const float* __restrict__ x,
                                                      const short* __restrict__ Wt,
                                                      const float* __restrict__ bias,
                                                      const int* __restrict__ src,
                                                      float* __restrict__ y) {
  __shared__ unsigned short Img[PP * PP * CP2];     // 67,280 B
  __shared__ unsigned short Aw[9 * OUTCn * CP2];    // 46,080 B
  __shared__ int srcl[Nn];                          // 2,916 B

  const int b = blockIdx.x;
  const int tid = threadIdx.x;
  const int lane = tid & 63;
  const int wv = tid >> 6;          // 0..7
  const int l16 = lane & 15;
  const int kg = lane >> 4;         // 0..3

  // one-time: load src row, zero padded image (borders stay zero forever)
  for (int n = tid; n < Nn; n += 512) srcl[n] = src[b * Nn + n];
  for (int k = tid; k < PP * PP * CP2 / 2; k += 512) ((unsigned int*)Img)[k] = 0u;

  // per-lane LDS byte bases (chunk-invariant)
  const int tilebase = wv * 6;
  int ibase[6];
#pragma unroll
  for (int t = 0; t < 6; ++t) {
    int nc = (tilebase + t) * 16 + l16;
    nc = nc > (Nn - 1) ? (Nn - 1) : nc;      // clamp dead cols
    int i = nc / Pn, j = nc - i * Pn;
    ibase[t] = (i * PP + j) * (CP2 * 2) + kg * 16;
  }
  const int abase = l16 * (CP2 * 2) + kg * 16;

  f32x4 acc[4][6];
#pragma unroll
  for (int a = 0; a < 4; ++a)
#pragma unroll
    for (int t = 0; t < 6; ++t) acc[a][t] = (f32x4){0.f, 0.f, 0.f, 0.f};

  const float* xb = x + (size_t)b * Cn * Nn;

  for (int ch = 0; ch < NCHUNK; ++ch) {
    const int c0 = ch * 32;
    __syncthreads();   // previous compute done before overwriting LDS

    // stage weight chunk: 576 rows (r*64+o) x 4 segs of 8 bf16
    for (int idx = tid; idx < 9 * OUTCn * 4; idx += 512) {
      int row = idx >> 2, seg = idx & 3;
      *(s16x8*)((char*)Aw + row * (CP2 * 2) + seg * 16) =
          *(const s16x8*)(Wt + row * CHP + c0 + seg * 8);
    }
    // stage gathered image chunk: 729 pixels x 8 groups of 4 channels
    for (int idx = tid; idx < Nn * 8; idx += 512) {
      int n = idx >> 3, cg = idx & 7;
      int s = srcl[n];
      int q = n / Pn;
      int p = n + 2 * q + PP + 1;            // padded pixel index
      int c = c0 + cg * 4;
      float v0, v1, v2, v3;
      if (c + 3 < CHn) {
        const float* xs = xb + (size_t)c * Nn + s;
        v0 = xs[0]; v1 = xs[Nn]; v2 = xs[2 * Nn]; v3 = xs[3 * Nn];
      } else {
        v0 = v1 = v2 = v3 = 0.f;
      }
      s16x4 w4 = {(short)f2bf(v0), (short)f2bf(v1), (short)f2bf(v2), (short)f2bf(v3)};
      *(s16x4*)((char*)Img + p * (CP2 * 2) + cg * 8) = w4;
    }
    __syncthreads();

    // compute: 9 shifts x 6 tiles x 4 o-tiles
#pragma unroll
    for (int r = 0; r < 9; ++r) {
      const int dr = r / 3, dc = r % 3;
      const int aoff = r * (OUTCn * CP2 * 2);
      s16x8 a0 = *(const s16x8*)((const char*)Aw + abase + aoff + 0 * (16 * CP2 * 2));
      s16x8 a1 = *(const s16x8*)((const char*)Aw + abase + aoff + 1 * (16 * CP2 * 2));
      s16x8 a2 = *(const s16x8*)((const char*)Aw + abase + aoff + 2 * (16 * CP2 * 2));
      s16x8 a3 = *(const s16x8*)((const char*)Aw + abase + aoff + 3 * (16 * CP2 * 2));
      const int ioff = (dr * PP + dc) * (CP2 * 2);
#pragma unroll
      for (int t = 0; t < 6; ++t) {
        s16x8 bfr = *(const s16x8*)((const char*)Img + ibase[t] + ioff);
        acc[0][t] = __builtin_amdgcn_mfma_f32_16x16x32_bf16(a0, bfr, acc[0][t], 0, 0, 0);
        acc[1][t] = __builtin_amdgcn_mfma_f32_16x16x32_bf16(a1, bfr, acc[1][t], 0, 0, 0);
        acc[2][t] = __builtin_amdgcn_mfma_f32_16x16x32_bf16(a2, bfr, acc[2][t], 0, 0, 0);
        acc[3][t] = __builtin_amdgcn_mfma_f32_16x16x32_bf16(a3, bfr, acc[3][t], 0, 0, 0);
      }
    }
  }

  // epilogue: D row (within o-tile) = kg*4 + q, col = l16
#pragma unroll
  for (int t = 0; t < 6; ++t) {
    int nc = (tilebase + t) * 16 + l16;
    if (nc < Nn) {
#pragma unroll
      for (int ot = 0; ot < 4; ++ot) {
#pragma unroll
        for (int q = 0; q < 4; ++q) {
          int o = ot * 16 + kg * 4 + q;
          y[((size_t)b * OUTCn + o) * Nn + nc] = acc[ot][t][q] + bias[o];
        }
      }
    }
  }
}

extern "C" void kernel_launch(void* const* d_in, const int* in_sizes, int n_in,
                              void* d_out, int out_size, void* d_ws, size_t ws_size,
                              hipStream_t stream) {
  const float* x = (const float*)d_in[0];
  const float* W = (const float*)d_in[1];
  const float* bias = (const float*)d_in[2];
  const int* rand_idx = (const int*)d_in[3];
  float* y = (float*)d_out;

  int* src = (int*)d_ws;                                   // 512*729*4 = 1,492,992 B
  short* Wt = (short*)((char*)d_ws + (size_t)Bn * Nn * 4); // 9*64*224*2 = 258,048 B (16B-aligned)

  src_kernel<<<Bn, 256, 0, stream>>>(x, rand_idx, src);
  wprep_kernel<<<(9 * OUTCn * CHP + 255) / 256, 256, 0, stream>>>(W, Wt);
  conv_kernel<<<Bn, 512, 0, stream>>>(x, Wt, bias, src, y);
}